// Round 3
// baseline (1053.373 us; speedup 1.0000x reference)
//
#include <hip/hip_runtime.h>
#include <math.h>

#define B_ 128
#define C_ 10
#define R_ 8192
#define I_ 8
#define O_ 16

#define RT_S 64   // r-tile per block in s_pass  (LDS W tile = 32 KB)
#define RT_L 8    // r-tile per block in logit_pass (LDS W tile = 4 KB)

// -------------------- transpose x[B,R,8] -> xt[R,B,8] --------------------
// 32x32 tiles of 32-byte (float4 x2) elements, LDS-staged, coalesced both sides.
__global__ __launch_bounds__(256) void transpose_x(const float* __restrict__ x,
                                                   float* __restrict__ xt) {
    __shared__ float4 tile[32 * 65];  // slot = b_local*65 + r_local*2 + q (pad kills conflicts)
    const int r0 = blockIdx.x * 32;
    const int b0 = blockIdx.y * 32;
#pragma unroll
    for (int k = 0; k < 8; ++k) {
        const int f = threadIdx.x + k * 256;              // float4 index in tile
        const int bl = f >> 6, rem = f & 63, rl = rem >> 1, q = rem & 1;
        const float4* src = (const float4*)(x + ((size_t)(b0 + bl) * R_ + r0 + rl) * I_);
        tile[bl * 65 + rl * 2 + q] = src[q];
    }
    __syncthreads();
#pragma unroll
    for (int k = 0; k < 8; ++k) {
        const int f = threadIdx.x + k * 256;
        const int rl = f >> 6, rem = f & 63, bl = rem >> 1, q = rem & 1;
        const float4 v = tile[bl * 65 + rl * 2 + q];
        ((float4*)(xt + ((size_t)(r0 + rl) * B_ + b0 + bl) * I_))[q] = v;
    }
}

// u[a][16], u[b][16] = x_a/x_b (8) @ W (8x16, LDS broadcast)
__device__ __forceinline__ void mat8x16_2(const float* __restrict__ xa,
                                          const float* __restrict__ xb,
                                          const float* __restrict__ wr,
                                          float* __restrict__ ua,
                                          float* __restrict__ ub) {
#pragma unroll
    for (int o = 0; o < 16; ++o) { ua[o] = 0.f; ub[o] = 0.f; }
#pragma unroll
    for (int i = 0; i < 8; ++i) {
        const float a = xa[i], b = xb[i];
#pragma unroll
        for (int q = 0; q < 4; ++q) {
            const float4 wv = ((const float4*)wr)[i * 4 + q];
            ua[q * 4 + 0] += a * wv.x; ua[q * 4 + 1] += a * wv.y;
            ua[q * 4 + 2] += a * wv.z; ua[q * 4 + 3] += a * wv.w;
            ub[q * 4 + 0] += b * wv.x; ub[q * 4 + 1] += b * wv.y;
            ub[q * 4 + 2] += b * wv.z; ub[q * 4 + 3] += b * wv.w;
        }
    }
}

// Drcp_t[r,b] = 1 / sum_c exp(u_hat[b,c,r,:] . vsum[b,c,:])
// grid: R_/RT_L blocks, 256 threads. Lane handles b={lane, lane+64}; wave handles 2 r's.
__global__ __launch_bounds__(256) void logit_pass(const float* __restrict__ xt,
                                                  const float* __restrict__ w,
                                                  const float* __restrict__ vsum,
                                                  float* __restrict__ Drcp_t) {
    __shared__ float wt[RT_L * 128];  // 4 KB
    const int r0 = blockIdx.x * RT_L;
    const int lane = threadIdx.x & 63;
    const int wave = threadIdx.x >> 6;
    const int b0 = lane, b1 = lane + 64;

    // xt[r, b, :] for 2 b x 2 r, registers across the c-loop (coalesced loads)
    float xi[2][2][8];
#pragma unroll
    for (int bb = 0; bb < 2; ++bb) {
        const int b = bb ? b1 : b0;
#pragma unroll
        for (int rr = 0; rr < 2; ++rr) {
            const int r = r0 + wave * 2 + rr;
            const float4* xp = (const float4*)(xt + ((size_t)r * B_ + b) * I_);
            const float4 a0 = xp[0], a1 = xp[1];
            xi[bb][rr][0] = a0.x; xi[bb][rr][1] = a0.y; xi[bb][rr][2] = a0.z; xi[bb][rr][3] = a0.w;
            xi[bb][rr][4] = a1.x; xi[bb][rr][5] = a1.y; xi[bb][rr][6] = a1.z; xi[bb][rr][7] = a1.w;
        }
    }

    float dacc[2][2] = {{0.f, 0.f}, {0.f, 0.f}};

#pragma unroll 1
    for (int c = 0; c < C_; ++c) {
        __syncthreads();
        const float4* wsrc = (const float4*)(w + ((size_t)c * R_ + r0) * (I_ * O_));
        ((float4*)wt)[threadIdx.x] = wsrc[threadIdx.x];
        __syncthreads();

        float vs0[16], vs1[16];
        {
            const float4* vp0 = (const float4*)(vsum + ((size_t)b0 * C_ + c) * O_);
            const float4* vp1 = (const float4*)(vsum + ((size_t)b1 * C_ + c) * O_);
#pragma unroll
            for (int q = 0; q < 4; ++q) {
                const float4 v0 = vp0[q], v1 = vp1[q];
                vs0[q * 4 + 0] = v0.x; vs0[q * 4 + 1] = v0.y; vs0[q * 4 + 2] = v0.z; vs0[q * 4 + 3] = v0.w;
                vs1[q * 4 + 0] = v1.x; vs1[q * 4 + 1] = v1.y; vs1[q * 4 + 2] = v1.z; vs1[q * 4 + 3] = v1.w;
            }
        }

#pragma unroll
        for (int rr = 0; rr < 2; ++rr) {
            const float* wr = wt + (wave * 2 + rr) * 128;
            float u0[16], u1[16];
            mat8x16_2(xi[0][rr], xi[1][rr], wr, u0, u1);
            float l0 = 0.f, l1 = 0.f;
#pragma unroll
            for (int o = 0; o < 16; ++o) { l0 += u0[o] * vs0[o]; l1 += u1[o] * vs1[o]; }
            dacc[0][rr] += __expf(l0);
            dacc[1][rr] += __expf(l1);
        }
    }

#pragma unroll
    for (int rr = 0; rr < 2; ++rr) {
        const int r = r0 + wave * 2 + rr;
        Drcp_t[(size_t)r * B_ + b0] = 1.0f / dacc[0][rr];
        Drcp_t[(size_t)r * B_ + b1] = 1.0f / dacc[1][rr];
    }
}

// s[b,c,o] += sum_{r in tile} c_ij * u_hat[b,c,r,o]
// grid: (R_/RT_S, C_). Lane handles b={lane, lane+64}; wave handles 16 contiguous r's.
__global__ __launch_bounds__(256) void s_pass(const float* __restrict__ xt,
                                              const float* __restrict__ w,
                                              const float* __restrict__ vsum,
                                              const float* __restrict__ Drcp_t,
                                              float* __restrict__ s,
                                              int mode) {
    __shared__ float wt[RT_S * 128];  // 32 KB, reused as reduce buffer
    const int c = blockIdx.y;
    const int r0 = blockIdx.x * RT_S;
    const int lane = threadIdx.x & 63;
    const int wave = threadIdx.x >> 6;
    const int b0 = lane, b1 = lane + 64;

    // stage W[c, r0:r0+RT_S, :, :] = 2048 float4, 8 per thread (coalesced)
    {
        const float4* wsrc = (const float4*)(w + ((size_t)c * R_ + r0) * (I_ * O_));
#pragma unroll
        for (int k = 0; k < 8; ++k)
            ((float4*)wt)[k * 256 + threadIdx.x] = wsrc[k * 256 + threadIdx.x];
    }

    float vs0[16], vs1[16];
    if (mode) {
        const float4* vp0 = (const float4*)(vsum + ((size_t)b0 * C_ + c) * O_);
        const float4* vp1 = (const float4*)(vsum + ((size_t)b1 * C_ + c) * O_);
#pragma unroll
        for (int q = 0; q < 4; ++q) {
            const float4 v0 = vp0[q], v1 = vp1[q];
            vs0[q * 4 + 0] = v0.x; vs0[q * 4 + 1] = v0.y; vs0[q * 4 + 2] = v0.z; vs0[q * 4 + 3] = v0.w;
            vs1[q * 4 + 0] = v1.x; vs1[q * 4 + 1] = v1.y; vs1[q * 4 + 2] = v1.z; vs1[q * 4 + 3] = v1.w;
        }
    }
    __syncthreads();

    float acc0[16], acc1[16];
#pragma unroll
    for (int o = 0; o < 16; ++o) { acc0[o] = 0.f; acc1[o] = 0.f; }

#pragma unroll 2
    for (int rr = 0; rr < 16; ++rr) {
        const int rl = wave * 16 + rr;
        const int r = r0 + rl;

        float xa[8], xb[8];
        {
            const float4* xp0 = (const float4*)(xt + ((size_t)r * B_ + b0) * I_);
            const float4* xp1 = (const float4*)(xt + ((size_t)r * B_ + b1) * I_);
            const float4 a0 = xp0[0], a1 = xp0[1], c0v = xp1[0], c1v = xp1[1];
            xa[0] = a0.x; xa[1] = a0.y; xa[2] = a0.z; xa[3] = a0.w;
            xa[4] = a1.x; xa[5] = a1.y; xa[6] = a1.z; xa[7] = a1.w;
            xb[0] = c0v.x; xb[1] = c0v.y; xb[2] = c0v.z; xb[3] = c0v.w;
            xb[4] = c1v.x; xb[5] = c1v.y; xb[6] = c1v.z; xb[7] = c1v.w;
        }

        const float* wr = wt + rl * 128;
        float u0[16], u1[16];
        mat8x16_2(xa, xb, wr, u0, u1);

        float c0, c1;
        if (mode == 0) {
            c0 = c1 = 1.0f / (float)C_;
        } else {
            float l0 = 0.f, l1 = 0.f;
#pragma unroll
            for (int o = 0; o < 16; ++o) { l0 += u0[o] * vs0[o]; l1 += u1[o] * vs1[o]; }
            c0 = __expf(l0) * Drcp_t[(size_t)r * B_ + b0];
            c1 = __expf(l1) * Drcp_t[(size_t)r * B_ + b1];
        }
#pragma unroll
        for (int o = 0; o < 16; ++o) { acc0[o] += c0 * u0[o]; acc1[o] += c1 * u1[o]; }
    }

    // block reduce: reuse wt as red[4][16][128] (lane-stride-1 -> conflict-free)
    __syncthreads();
    float* red = wt;
#pragma unroll
    for (int o = 0; o < 16; ++o) {
        red[wave * 2048 + o * 128 + b0] = acc0[o];
        red[wave * 2048 + o * 128 + b1] = acc1[o];
    }
    __syncthreads();
#pragma unroll
    for (int k = 0; k < 8; ++k) {
        const int idx = threadIdx.x + k * 256;  // idx = o*128 + b, lanes consecutive
        const float v = red[idx] + red[2048 + idx] + red[4096 + idx] + red[6144 + idx];
        const int o = idx >> 7, b = idx & 127;
        atomicAdd(&s[((size_t)b * C_ + c) * O_ + o], v);
    }
}

// Squash: v = squash(s). mode 0: vsum = v; mode 1: vsum += v; mode 2: out = v
__global__ __launch_bounds__(256) void v_pass(const float* __restrict__ s,
                                              float* __restrict__ vsum,
                                              float* __restrict__ out,
                                              int mode) {
    const int t = blockIdx.x * 256 + threadIdx.x;  // over B*C = 1280
    if (t >= B_ * C_) return;
    float sv[16];
    float sq = 0.f;
#pragma unroll
    for (int o = 0; o < 16; ++o) {
        sv[o] = s[(size_t)t * O_ + o];
        sq += sv[o] * sv[o];
    }
    const float scale = sq / ((1.0f + sq) * sqrtf(sq + 1e-8f));
    if (mode == 0) {
#pragma unroll
        for (int o = 0; o < 16; ++o) vsum[(size_t)t * O_ + o] = scale * sv[o];
    } else if (mode == 1) {
#pragma unroll
        for (int o = 0; o < 16; ++o) vsum[(size_t)t * O_ + o] += scale * sv[o];
    } else {
#pragma unroll
        for (int o = 0; o < 16; ++o) out[(size_t)t * O_ + o] = scale * sv[o];
    }
}

extern "C" void kernel_launch(void* const* d_in, const int* in_sizes, int n_in,
                              void* d_out, int out_size, void* d_ws, size_t ws_size,
                              hipStream_t stream) {
    const float* x = (const float*)d_in[0];        // [B,R,I]
    const float* w = (const float*)d_in[1];        // [C,R,I,O]
    float* out = (float*)d_out;                    // [B,C,O]

    float* xt   = (float*)d_ws;                    // R*B*I = 8.39M floats (33.5 MB)
    float* s    = xt + (size_t)R_ * B_ * I_;       // 20480 floats
    float* vsum = s + (size_t)B_ * C_ * O_;        // 20480 floats
    float* Drcp = vsum + (size_t)B_ * C_ * O_;     // R*B = 1.05M floats (4.2 MB)

    const dim3 tgrid(R_ / 32, B_ / 32);
    const dim3 sgrid(R_ / RT_S, C_);   // (128, 10)
    const dim3 lgrid(R_ / RT_L);       // 1024
    const dim3 vgrid((B_ * C_ + 255) / 256);

    transpose_x<<<tgrid, 256, 0, stream>>>(x, xt);

    // iteration 0: c_ij uniform = 1/C
    hipMemsetAsync(s, 0, (size_t)B_ * C_ * O_ * sizeof(float), stream);
    s_pass<<<sgrid, 256, 0, stream>>>(xt, w, nullptr, nullptr, s, 0);
    v_pass<<<vgrid, 256, 0, stream>>>(s, vsum, out, 0);

    // iteration 1
    hipMemsetAsync(s, 0, (size_t)B_ * C_ * O_ * sizeof(float), stream);
    logit_pass<<<lgrid, 256, 0, stream>>>(xt, w, vsum, Drcp);
    s_pass<<<sgrid, 256, 0, stream>>>(xt, w, vsum, Drcp, s, 1);
    v_pass<<<vgrid, 256, 0, stream>>>(s, vsum, out, 1);

    // iteration 2 (final: write v to out)
    hipMemsetAsync(s, 0, (size_t)B_ * C_ * O_ * sizeof(float), stream);
    logit_pass<<<lgrid, 256, 0, stream>>>(xt, w, vsum, Drcp);
    s_pass<<<sgrid, 256, 0, stream>>>(xt, w, vsum, Drcp, s, 1);
    v_pass<<<vgrid, 256, 0, stream>>>(s, vsum, out, 2);
}